// Round 1
// baseline (208.077 us; speedup 1.0000x reference)
//
#include <hip/hip_runtime.h>

#define SEQ 2048
#define DMODEL 1024
#define HEADS 16
#define DH 64
// fold (1/sqrt(64)) * log2(e) into Wq so scores arrive in exp2 domain
#define QSCALE 0.180336880f

typedef __attribute__((ext_vector_type(8))) short short8;
typedef __attribute__((ext_vector_type(4))) float f32x4;

__device__ __forceinline__ ushort f2bf(float x) {
  union { float f; unsigned u; } v; v.f = x;
  return (ushort)((v.u + 0x7fffu + ((v.u >> 16) & 1u)) >> 16);
}

// async global->LDS, 16B per lane. LDS dest = wave-uniform base + lane*16.
__device__ __forceinline__ void gld16(const ushort* g, ushort* l) {
  __builtin_amdgcn_global_load_lds(
      (const __attribute__((address_space(1))) unsigned int*)g,
      (__attribute__((address_space(3))) unsigned int*)l, 16, 0, 0);
}

// fragment-major index for Q/K [bh][s>>4][d>>5][lane q*16+ln][j=d&7]
__device__ __forceinline__ size_t qk_idx(int bh, int s, int d) {
  return ((((size_t)bh * (SEQ / 16) + (s >> 4)) * 2 + (d >> 5)) * 64 +
          ((d >> 3) & 3) * 16 + (s & 15)) * 8 + (d & 7);
}
// fragment-major index for V^T, CHUNK-major: [bh][s>>5][d>>4][lane][j=s&7]
// (s-chunk outermost so one kt iteration's 8 fragments are 8 KB contiguous)
__device__ __forceinline__ size_t v_idx(int bh, int s, int d) {
  return ((((size_t)bh * (SEQ / 32) + (s >> 5)) * 4 + (d >> 4)) * 64 +
          ((s >> 3) & 3) * 16 + (d & 15)) * 8 + (s & 7);
}

// ---------------------------------------------------------------------------
// Fused prologue. z=0/1: fp32->bf16 cast of patch/pixel (4x float4/thread).
// z=2..5: transpose-cast Wq*QSCALE / Wk / Wv / Wo to [N][K] bf16.
// ---------------------------------------------------------------------------
__global__ __launch_bounds__(256) void prologue(
    const float* __restrict__ patch, const float* __restrict__ pixel,
    const float* __restrict__ W0, const float* __restrict__ W1,
    const float* __restrict__ W2, const float* __restrict__ W3,
    ushort* __restrict__ pb, ushort* __restrict__ xb,
    ushort* __restrict__ O0, ushort* __restrict__ O1,
    ushort* __restrict__ O2, ushort* __restrict__ O3) {
  const int z = blockIdx.z;
  const int tx = threadIdx.x, ty = threadIdx.y;
  if (z < 2) {
    const float4* in = (const float4*)(z ? pixel : patch);
    ushort4* out = (ushort4*)(z ? xb : pb);
    const int base = (blockIdx.y * 32 + blockIdx.x) * 256 + ty * 32 + tx;
#pragma unroll
    for (int rep = 0; rep < 4; ++rep) {
      const int i = base + rep * 262144;
      float4 f = in[i];
      out[i] = make_ushort4(f2bf(f.x), f2bf(f.y), f2bf(f.z), f2bf(f.w));
    }
    return;
  }
  __shared__ float tile[32][33];
  const int zz = z - 2;
  const float* in = zz == 0 ? W0 : zz == 1 ? W1 : zz == 2 ? W2 : W3;
  ushort* out = zz == 0 ? O0 : zz == 1 ? O1 : zz == 2 ? O2 : O3;
  const float scale = zz == 0 ? QSCALE : 1.0f;
  const int n0 = blockIdx.x * 32, k0 = blockIdx.y * 32;
#pragma unroll
  for (int i = 0; i < 4; ++i)
    tile[ty + i * 8][tx] = in[(size_t)(k0 + ty + i * 8) * DMODEL + n0 + tx];
  __syncthreads();
#pragma unroll
  for (int i = 0; i < 4; ++i)
    out[(size_t)(n0 + ty + i * 8) * DMODEL + k0 + tx] =
        f2bf(tile[tx][ty + i * 8] * scale);
}

// ---------------------------------------------------------------------------
// Fused Q/K/V projection GEMM, global_load_lds(16B) staging, XOR-swizzled on
// the GLOBAL side. 128x128 tile, BK=64, 4 waves. Epilogues scatter to the
// fragment-major layouts consumed by flash_mfma.
// ---------------------------------------------------------------------------
__global__ __launch_bounds__(256) void mfma_gemm_qkv(
    const ushort* __restrict__ pb, const ushort* __restrict__ xb,
    const ushort* __restrict__ wqt, const ushort* __restrict__ wkt,
    const ushort* __restrict__ wvt, ushort* __restrict__ qws,
    ushort* __restrict__ kws, ushort* __restrict__ vws) {
  __shared__ __align__(16) ushort As[128 * 64];
  __shared__ __align__(16) ushort Bs[128 * 64];
  const int z = blockIdx.z;
  const ushort* A = (z == 0) ? pb : xb;
  const ushort* Bt = (z == 0) ? wqt : (z == 1) ? wkt : wvt;

  const int t = threadIdx.x;
  const int w = t >> 6, lane = t & 63, ln = lane & 15, q = lane >> 4;
  const int wm = w & 1, wn = w >> 1;
  const int row0 = blockIdx.y * 128, col0 = blockIdx.x * 128;
  const int sw = ln & 7;

  f32x4 acc[4][4];
#pragma unroll
  for (int i = 0; i < 4; ++i)
#pragma unroll
    for (int j = 0; j < 4; ++j) acc[i][j] = (f32x4){0.f, 0.f, 0.f, 0.f};

  for (int k0 = 0; k0 < DMODEL; k0 += 64) {
    __syncthreads();  // prior frag reads done
#pragma unroll
    for (int rep = 0; rep < 4; ++rep) {
      const int u0 = rep * 256 + w * 64;
      const int u = u0 + lane;
      const int r = u >> 3, gl = (u & 7) ^ (r & 7);
      gld16(&A[(size_t)(row0 + r) * DMODEL + k0 + gl * 8], &As[u0 * 8]);
      gld16(&Bt[(size_t)(col0 + r) * DMODEL + k0 + gl * 8], &Bs[u0 * 8]);
    }
    __syncthreads();  // vmcnt drain
#pragma unroll
    for (int ks = 0; ks < 2; ++ks) {
      short8 af[4], bf[4];
#pragma unroll
      for (int rt = 0; rt < 4; ++rt)
        af[rt] = *(const short8*)&As[(wm * 64 + rt * 16 + ln) * 64 +
                                     (((ks * 4 + q) ^ sw) * 8)];
#pragma unroll
      for (int ct = 0; ct < 4; ++ct)
        bf[ct] = *(const short8*)&Bs[(wn * 64 + ct * 16 + ln) * 64 +
                                     (((ks * 4 + q) ^ sw) * 8)];
#pragma unroll
      for (int rt = 0; rt < 4; ++rt)
#pragma unroll
        for (int ct = 0; ct < 4; ++ct)
          acc[rt][ct] = __builtin_amdgcn_mfma_f32_16x16x32_bf16(af[rt], bf[ct],
                                                                acc[rt][ct], 0, 0, 0);
    }
  }

  if (z < 2) {
    ushort* dst = z == 0 ? qws : kws;
#pragma unroll
    for (int rt = 0; rt < 4; ++rt)
#pragma unroll
      for (int ct = 0; ct < 4; ++ct) {
        const int c = col0 + wn * 64 + ct * 16 + ln;
        const int h = c >> 6, d = c & 63;
#pragma unroll
        for (int reg = 0; reg < 4; ++reg) {
          const int r = row0 + wm * 64 + rt * 16 + q * 4 + reg;
          const int b = r >> 11, s = r & (SEQ - 1);
          dst[qk_idx(b * HEADS + h, s, d)] = f2bf(acc[rt][ct][reg]);
        }
      }
  } else {
#pragma unroll
    for (int rt = 0; rt < 4; ++rt)
#pragma unroll
      for (int ct = 0; ct < 4; ++ct) {
        const int c = col0 + wn * 64 + ct * 16 + ln;
        const int h = c >> 6, d = c & 63;
        const int r0 = row0 + wm * 64 + rt * 16 + q * 4;
        const int b = r0 >> 11, s0 = r0 & (SEQ - 1);
        ushort4 u4 = make_ushort4(f2bf(acc[rt][ct][0]), f2bf(acc[rt][ct][1]),
                                  f2bf(acc[rt][ct][2]), f2bf(acc[rt][ct][3]));
        *(ushort4*)&vws[v_idx(b * HEADS + h, s0, d)] = u4;
      }
  }
}

// ---------------------------------------------------------------------------
// Flash attention v5: Q-tile 64 (4 waves x 16 rows), grid (32 bh, 32 qt) =
// 1024 blocks -> 4 blocks/CU, 16 waves/CU (2x v4's occupancy). K is DMA-
// staged double-buffered in LDS (one barrier/iter); V is read DIRECTLY from
// global (chunk-major fragments, hoisted to iteration top so HBM/L2 latency
// hides under QK^T+softmax). Co-resident blocks on a CU share the same bh
// (grid 32x32, 1024%256: ids = c mod 256 => same bh) so K/V hit L1/L2.
// LDS 25.6 KB. Ps stride 76 ushorts: scalar P-writes land on all 32 banks.
// ---------------------------------------------------------------------------
__global__ __launch_bounds__(256, 4) void flash_mfma(
    const ushort* __restrict__ Qg, const ushort* __restrict__ Kg,
    const ushort* __restrict__ Vg, ushort* __restrict__ Og) {
  __shared__ __align__(16) ushort Kst[2][8 * 512];  // 2 x 8 KB
  __shared__ __align__(16) ushort Ps[64 * 76];      // 9.5 KB, wave-private rows

  const int t = threadIdx.x;
  const int w = t >> 6, lane = t & 63, ln = lane & 15, q = lane >> 4;
  const int bh = blockIdx.x;   // 0..31  (XCD-pinning: id%8 = bh%8)
  const int qt = blockIdx.y;   // 0..31  (64-row Q tile)

  const ushort* qg = Qg + (size_t)bh * SEQ * DH;
  const ushort* kg = Kg + (size_t)bh * SEQ * DH;
  const ushort* vg = Vg + (size_t)bh * DH * SEQ;

  // Q A-fragments (1 row-tile x 2 k-halves), coalesced lane*16B loads
  short8 qf[2];
#pragma unroll
  for (int ks = 0; ks < 2; ++ks)
    qf[ks] = *(const short8*)
        &qg[(((size_t)(qt * 4 + w) * 2 + ks) * 64 + lane) * 8];

  float l_i[4] = {0.f, 0.f, 0.f, 0.f};
  f32x4 acc_o[4];
#pragma unroll
  for (int nt = 0; nt < 4; ++nt) acc_o[nt] = (f32x4){0.f, 0.f, 0.f, 0.f};

  // stage kt=0 into buffer 0 (wave w issues frags w*2, w*2+1)
#pragma unroll
  for (int i = 0; i < 2; ++i) {
    const int f = w * 2 + i;
    gld16(&kg[(size_t)f * 512 + lane * 8], &Kst[0][f * 512]);
  }
  __syncthreads();  // drain prologue DMA

  for (int kt = 0; kt < SEQ / 64; ++kt) {
    const int cur = kt & 1;
    // issue NEXT iter's K DMA first (lands during this iter's compute)
    if (kt + 1 < SEQ / 64) {
#pragma unroll
      for (int i = 0; i < 2; ++i) {
        const int f = w * 2 + i;
        gld16(&kg[(size_t)((kt + 1) * 8 + f) * 512 + lane * 8],
              &Kst[cur ^ 1][f * 512]);
      }
    }

    // hoist THIS iter's V fragments (global, chunk-major, L1/L2-resident):
    // latency hides under QK^T + softmax below
    short8 bv[2][4];
#pragma unroll
    for (int ks2 = 0; ks2 < 2; ++ks2)
#pragma unroll
      for (int nt = 0; nt < 4; ++nt)
        bv[ks2][nt] = *(const short8*)
            &vg[((size_t)((kt * 2 + ks2) * 4 + nt) * 64 + lane) * 8];

    // S = Q @ K^T (wave: 16 x 64)
    f32x4 accs[4];
#pragma unroll
    for (int ct = 0; ct < 4; ++ct) accs[ct] = (f32x4){0.f, 0.f, 0.f, 0.f};
#pragma unroll
    for (int ks = 0; ks < 2; ++ks)
#pragma unroll
      for (int ct = 0; ct < 4; ++ct) {
        const short8 bfr = *(const short8*)&Kst[cur][(ct * 2 + ks) * 512 + lane * 8];
        accs[ct] = __builtin_amdgcn_mfma_f32_16x16x32_bf16(
            qf[ks], bfr, accs[ct], 0, 0, 0);
      }

    // p = 2^s (Q pre-scaled), lane-partial l, P -> wave-private LDS rows
#pragma unroll
    for (int ct = 0; ct < 4; ++ct)
#pragma unroll
      for (int reg = 0; reg < 4; ++reg) {
        const float p = __builtin_amdgcn_exp2f(accs[ct][reg]);
        l_i[reg] += p;
        union { float f; unsigned u; } v; v.f = p;
        Ps[(w * 16 + q * 4 + reg) * 76 + ct * 16 + ln] =
            (ushort)((v.u + 0x8000u) >> 16);
      }

    // O += P @ V (V fragments already in registers)
#pragma unroll
    for (int ks2 = 0; ks2 < 2; ++ks2) {
      const short8 pa = *(const short8*)&Ps[(w * 16 + ln) * 76 + ks2 * 32 + q * 8];
#pragma unroll
      for (int nt = 0; nt < 4; ++nt)
        acc_o[nt] = __builtin_amdgcn_mfma_f32_16x16x32_bf16(
            pa, bv[ks2][nt], acc_o[nt], 0, 0, 0);
    }

    __syncthreads();  // single barrier: next K DMA drained + buffer swappable
  }

  // epilogue: reduce l over the quad's 16 lanes, normalize, write aws bf16
  const int b = bh >> 4, h = bh & 15;
#pragma unroll
  for (int reg = 0; reg < 4; ++reg) {
    float l = l_i[reg];
    l += __shfl_xor(l, 1, 16);
    l += __shfl_xor(l, 2, 16);
    l += __shfl_xor(l, 4, 16);
    l += __shfl_xor(l, 8, 16);
    const float inv = 1.0f / l;
    const int s = qt * 64 + w * 16 + q * 4 + reg;
#pragma unroll
    for (int nt = 0; nt < 4; ++nt)
      Og[(size_t)(b * SEQ + s) * DMODEL + h * DH + nt * 16 + ln] =
          f2bf(acc_o[nt][reg] * inv);
  }
}

// ---------------------------------------------------------------------------
// Output projection: out = aws[4096,1024] @ WoT^T + bo (fp32). 64x128 tile,
// BK=64, global_load_lds staging, 512 blocks.
// ---------------------------------------------------------------------------
__global__ __launch_bounds__(256) void mfma_gemm_out(const ushort* __restrict__ A,
                                                     const ushort* __restrict__ Bt,
                                                     const float* __restrict__ bias,
                                                     float* __restrict__ dst) {
  __shared__ __align__(16) ushort As[64 * 64];
  __shared__ __align__(16) ushort Bs[128 * 64];
  const int t = threadIdx.x;
  const int w = t >> 6, lane = t & 63, ln = lane & 15, q = lane >> 4;
  const int wm = w & 1, wn = w >> 1;
  const int row0 = blockIdx.y * 64, col0 = blockIdx.x * 128;
  const int sw = ln & 7;

  f32x4 acc[2][4];
#pragma unroll
  for (int i = 0; i < 2; ++i)
#pragma unroll
    for (int j = 0; j < 4; ++j) acc[i][j] = (f32x4){0.f, 0.f, 0.f, 0.f};

  for (int k0 = 0; k0 < DMODEL; k0 += 64) {
    __syncthreads();
#pragma unroll
    for (int rep = 0; rep < 2; ++rep) {
      const int u0 = rep * 256 + w * 64;
      const int u = u0 + lane;
      const int r = u >> 3, gl = (u & 7) ^ (r & 7);
      gld16(&A[(size_t)(row0 + r) * DMODEL + k0 + gl * 8], &As[u0 * 8]);
    }
#pragma unroll
    for (int rep = 0; rep < 4; ++rep) {
      const int u0 = rep * 256 + w * 64;
      const int u = u0 + lane;
      const int r = u >> 3, gl = (u & 7) ^ (r & 7);
      gld16(&Bt[(size_t)(col0 + r) * DMODEL + k0 + gl * 8], &Bs[u0 * 8]);
    }
    __syncthreads();
#pragma unroll
    for (int ks = 0; ks < 2; ++ks) {
      short8 af[2], bf[4];
#pragma unroll
      for (int rt = 0; rt < 2; ++rt)
        af[rt] = *(const short8*)&As[(wm * 32 + rt * 16 + ln) * 64 +
                                     (((ks * 4 + q) ^ sw) * 8)];
#pragma unroll
      for (int ct = 0; ct < 4; ++ct)
        bf[ct] = *(const short8*)&Bs[(wn * 64 + ct * 16 + ln) * 64 +
                                     (((ks * 4 + q) ^ sw) * 8)];
#pragma unroll
      for (int rt = 0; rt < 2; ++rt)
#pragma unroll
        for (int ct = 0; ct < 4; ++ct)
          acc[rt][ct] = __builtin_amdgcn_mfma_f32_16x16x32_bf16(af[rt], bf[ct],
                                                                acc[rt][ct], 0, 0, 0);
    }
  }

#pragma unroll
  for (int rt = 0; rt < 2; ++rt)
#pragma unroll
    for (int ct = 0; ct < 4; ++ct) {
      const int c = col0 + wn * 64 + ct * 16 + ln;
      const float bi = bias[c];
#pragma unroll
      for (int reg = 0; reg < 4; ++reg) {
        const int r = row0 + wm * 32 + rt * 16 + q * 4 + reg;
        dst[(size_t)r * DMODEL + c] = acc[rt][ct][reg] + bi;
      }
    }
}

extern "C" void kernel_launch(void* const* d_in, const int* in_sizes, int n_in,
                              void* d_out, int out_size, void* d_ws,
                              size_t ws_size, hipStream_t stream) {
  const float* patch = (const float*)d_in[0];
  const float* pixel = (const float*)d_in[1];
  const float* Wq = (const float*)d_in[2];
  const float* Wk = (const float*)d_in[3];
  const float* Wv = (const float*)d_in[4];
  const float* Wo = (const float*)d_in[5];
  const float* bo = (const float*)d_in[6];
  float* out = (float*)d_out;

  const size_t E = (size_t)2 * SEQ * DMODEL;  // 4,194,304
  const size_t W = (size_t)DMODEL * DMODEL;   // 1,048,576
  ushort* pb  = (ushort*)d_ws;      // patch bf16
  ushort* xb  = pb + E;             // pixel bf16
  ushort* wqt = xb + E;             // Wq^T * QSCALE bf16 [N][K]
  ushort* wkt = wqt + W;
  ushort* wvt = wkt + W;
  ushort* wot = wvt + W;            // live until mfma_gemm_out
  ushort* qws = wot + W;            // Q fragment-major
  ushort* kws = qws + E;            // K fragment-major
  ushort* vws = kws + E;            // V^T fragment-major (chunk-major)
  ushort* aws = vws + E;            // [4096][1024] row-major bf16

  prologue<<<dim3(32, 32, 6), dim3(32, 8), 0, stream>>>(
      patch, pixel, Wq, Wk, Wv, Wo, pb, xb, wqt, wkt, wvt, wot);
  mfma_gemm_qkv<<<dim3(8, 32, 3), 256, 0, stream>>>(pb, xb, wqt, wkt, wvt,
                                                    qws, kws, vws);
  flash_mfma<<<dim3(32, 32), 256, 0, stream>>>(qws, kws, vws, aws);
  mfma_gemm_out<<<dim3(8, 64), 256, 0, stream>>>(aws, wot, bo, out);
}

// Round 2
// 190.775 us; speedup vs baseline: 1.0907x; 1.0907x over previous
//
#include <hip/hip_runtime.h>

#define SEQ 2048
#define DMODEL 1024
#define HEADS 16
#define DH 64
// fold (1/sqrt(64)) * log2(e) into Wq so scores arrive in exp2 domain
#define QSCALE 0.180336880f

typedef __attribute__((ext_vector_type(8))) short short8;
typedef __attribute__((ext_vector_type(4))) float f32x4;
typedef __attribute__((ext_vector_type(16))) float f32x16;
typedef __attribute__((ext_vector_type(2))) unsigned int uint2v;
typedef __attribute__((ext_vector_type(4))) unsigned int uint4v;

__device__ __forceinline__ ushort f2bf(float x) {
  union { float f; unsigned u; } v; v.f = x;
  return (ushort)((v.u + 0x7fffu + ((v.u >> 16) & 1u)) >> 16);
}

// async global->LDS, 16B per lane. LDS dest = wave-uniform base + lane*16.
__device__ __forceinline__ void gld16(const ushort* g, ushort* l) {
  __builtin_amdgcn_global_load_lds(
      (const __attribute__((address_space(1))) unsigned int*)g,
      (__attribute__((address_space(3))) unsigned int*)l, 16, 0, 0);
}

// ---------------------------------------------------------------------------
// Fused prologue. z=0/1: fp32->bf16 cast of patch/pixel (4x float4/thread).
// z=2..5: transpose-cast Wq*QSCALE / Wk / Wv / Wo to [N][K] bf16.
// ---------------------------------------------------------------------------
__global__ __launch_bounds__(256) void prologue(
    const float* __restrict__ patch, const float* __restrict__ pixel,
    const float* __restrict__ W0, const float* __restrict__ W1,
    const float* __restrict__ W2, const float* __restrict__ W3,
    ushort* __restrict__ pb, ushort* __restrict__ xb,
    ushort* __restrict__ O0, ushort* __restrict__ O1,
    ushort* __restrict__ O2, ushort* __restrict__ O3) {
  const int z = blockIdx.z;
  const int tx = threadIdx.x, ty = threadIdx.y;
  if (z < 2) {
    const float4* in = (const float4*)(z ? pixel : patch);
    ushort4* out = (ushort4*)(z ? xb : pb);
    const int base = (blockIdx.y * 32 + blockIdx.x) * 256 + ty * 32 + tx;
#pragma unroll
    for (int rep = 0; rep < 4; ++rep) {
      const int i = base + rep * 262144;
      float4 f = in[i];
      out[i] = make_ushort4(f2bf(f.x), f2bf(f.y), f2bf(f.z), f2bf(f.w));
    }
    return;
  }
  __shared__ float tile[32][33];
  const int zz = z - 2;
  const float* in = zz == 0 ? W0 : zz == 1 ? W1 : zz == 2 ? W2 : W3;
  ushort* out = zz == 0 ? O0 : zz == 1 ? O1 : zz == 2 ? O2 : O3;
  const float scale = zz == 0 ? QSCALE : 1.0f;
  const int n0 = blockIdx.x * 32, k0 = blockIdx.y * 32;
#pragma unroll
  for (int i = 0; i < 4; ++i)
    tile[ty + i * 8][tx] = in[(size_t)(k0 + ty + i * 8) * DMODEL + n0 + tx];
  __syncthreads();
#pragma unroll
  for (int i = 0; i < 4; ++i)
    out[(size_t)(n0 + ty + i * 8) * DMODEL + k0 + tx] =
        f2bf(tile[tx][ty + i * 8] * scale);
}

// ---------------------------------------------------------------------------
// Fused Q/K/V projection GEMM, global_load_lds(16B) staging, XOR-swizzled on
// the GLOBAL side. 128x128 tile, BK=64, 4 waves. Q/K epilogues write plain
// row-major [4096][1024] bf16 (consumed directly by flash 32x32 fragments);
// V epilogue writes V^T [bh][64][SEQ].
// ---------------------------------------------------------------------------
__global__ __launch_bounds__(256) void mfma_gemm_qkv(
    const ushort* __restrict__ pb, const ushort* __restrict__ xb,
    const ushort* __restrict__ wqt, const ushort* __restrict__ wkt,
    const ushort* __restrict__ wvt, ushort* __restrict__ qws,
    ushort* __restrict__ kws, ushort* __restrict__ vws) {
  __shared__ __align__(16) ushort As[128 * 64];
  __shared__ __align__(16) ushort Bs[128 * 64];
  const int z = blockIdx.z;
  const ushort* A = (z == 0) ? pb : xb;
  const ushort* Bt = (z == 0) ? wqt : (z == 1) ? wkt : wvt;

  const int t = threadIdx.x;
  const int w = t >> 6, lane = t & 63, ln = lane & 15, q = lane >> 4;
  const int wm = w & 1, wn = w >> 1;
  const int row0 = blockIdx.y * 128, col0 = blockIdx.x * 128;
  const int sw = ln & 7;

  f32x4 acc[4][4];
#pragma unroll
  for (int i = 0; i < 4; ++i)
#pragma unroll
    for (int j = 0; j < 4; ++j) acc[i][j] = (f32x4){0.f, 0.f, 0.f, 0.f};

  for (int k0 = 0; k0 < DMODEL; k0 += 64) {
    __syncthreads();  // prior frag reads done
#pragma unroll
    for (int rep = 0; rep < 4; ++rep) {
      const int u0 = rep * 256 + w * 64;
      const int u = u0 + lane;
      const int r = u >> 3, gl = (u & 7) ^ (r & 7);
      gld16(&A[(size_t)(row0 + r) * DMODEL + k0 + gl * 8], &As[u0 * 8]);
      gld16(&Bt[(size_t)(col0 + r) * DMODEL + k0 + gl * 8], &Bs[u0 * 8]);
    }
    __syncthreads();  // vmcnt drain
#pragma unroll
    for (int ks = 0; ks < 2; ++ks) {
      short8 af[4], bf[4];
#pragma unroll
      for (int rt = 0; rt < 4; ++rt)
        af[rt] = *(const short8*)&As[(wm * 64 + rt * 16 + ln) * 64 +
                                     (((ks * 4 + q) ^ sw) * 8)];
#pragma unroll
      for (int ct = 0; ct < 4; ++ct)
        bf[ct] = *(const short8*)&Bs[(wn * 64 + ct * 16 + ln) * 64 +
                                     (((ks * 4 + q) ^ sw) * 8)];
#pragma unroll
      for (int rt = 0; rt < 4; ++rt)
#pragma unroll
        for (int ct = 0; ct < 4; ++ct)
          acc[rt][ct] = __builtin_amdgcn_mfma_f32_16x16x32_bf16(af[rt], bf[ct],
                                                                acc[rt][ct], 0, 0, 0);
    }
  }

  if (z < 2) {
    ushort* dst = z == 0 ? qws : kws;  // row-major [4096][1024]
#pragma unroll
    for (int rt = 0; rt < 4; ++rt)
#pragma unroll
      for (int ct = 0; ct < 4; ++ct) {
        const int c = col0 + wn * 64 + ct * 16 + ln;
#pragma unroll
        for (int reg = 0; reg < 4; ++reg) {
          const int r = row0 + wm * 64 + rt * 16 + q * 4 + reg;
          dst[(size_t)r * DMODEL + c] = f2bf(acc[rt][ct][reg]);
        }
      }
  } else {
    // V^T: vws[bh][64][SEQ]
#pragma unroll
    for (int rt = 0; rt < 4; ++rt)
#pragma unroll
      for (int ct = 0; ct < 4; ++ct) {
        const int c = col0 + wn * 64 + ct * 16 + ln;
        const int hh = c >> 6, d = c & 63;
        const int r0 = row0 + wm * 64 + rt * 16 + q * 4;
        const int bb = r0 >> 11, s0 = r0 & (SEQ - 1);
        ushort4 u4 = make_ushort4(f2bf(acc[rt][ct][0]), f2bf(acc[rt][ct][1]),
                                  f2bf(acc[rt][ct][2]), f2bf(acc[rt][ct][3]));
        *(ushort4*)&vws[((size_t)(bb * HEADS + hh) * DH + d) * SEQ + s0] = u4;
      }
  }
}

// ---------------------------------------------------------------------------
// Flash attention v6 (LDS-traffic attack): 32x32x16 MFMAs, 32 q-rows/wave,
// 4 waves = 128-row Q tile, grid (32 bh, 16 qt) = 512 blocks = 2/CU.
// QK^T computed SWAPPED (A=K, B=Q -> S^T) so each lane owns a full q-column
// of P; softmax + bf16 pack (v_cvt_pk_bf16_f32) + permlane32_swap build the
// PV A-fragments ENTIRELY IN REGISTERS -> the P LDS round-trip (16 b16
// writes + reads per wave-iter, ~55% of old LDS cycles) is gone. K and V
// staged double-buffered via global_load_lds, XOR-swizzled (row stride 128B
// would be a 32-way conflict); one barrier per iter. LDS traffic per CU
// drops 109K -> ~49K cycles.
// ---------------------------------------------------------------------------
__global__ __launch_bounds__(256, 2) void flash_mfma(
    const ushort* __restrict__ Qg, const ushort* __restrict__ Kg,
    const ushort* __restrict__ Vg, ushort* __restrict__ Og) {
  __shared__ __align__(16) ushort Kst[2][64 * 64];  // 2 x 8 KB, rows = key
  __shared__ __align__(16) ushort Vst[2][64 * 64];  // 2 x 8 KB, rows = d

  const int t = threadIdx.x;
  const int w = t >> 6, lane = t & 63;
  const int l31 = lane & 31, hi = lane >> 5, l7 = lane & 7, l8 = lane >> 3;
  const int bh = blockIdx.x;  // 0..31 (XCD-pinning: id%8 = bh%8)
  const int qt = blockIdx.y;  // 0..15 (128-row Q tile)
  const int b = bh >> 4, h = bh & 15;

  const ushort* qrow = Qg + ((size_t)b * SEQ) * DMODEL + h * DH;  // [s][1024]
  const ushort* krow = Kg + ((size_t)b * SEQ) * DMODEL + h * DH;
  const ushort* vg = Vg + (size_t)bh * DH * SEQ;                  // [64][SEQ]

  // Q B-fragments: lane: qcol = l31, k = ks*16 + hi*8 + j  (row-major read)
  short8 qf[4];
#pragma unroll
  for (int ks = 0; ks < 4; ++ks)
    qf[ks] = *(const short8*)
        &qrow[(size_t)(qt * 128 + w * 32 + l31) * DMODEL + ks * 16 + hi * 8];

  f32x16 acc_o[2];
#pragma unroll
  for (int db = 0; db < 2; ++db)
#pragma unroll
    for (int e = 0; e < 16; ++e) acc_o[db][e] = 0.f;
  float l_i = 0.f;

  // DMA assignment: w0: K f0-3, w1: K f4-7, w2: V f0-3, w3: V f4-7.
  // frag f covers 8 rows x 64 cols; lane: row f*8+l8, 16B chunk (l7^l8)
  // (global-side XOR swizzle; LDS dest is linear).
  const int fbase = (w & 1) * 4;
  const bool isV = (w >= 2);
  const int swz = (l7 ^ l8) * 8;

  {
#pragma unroll
    for (int i = 0; i < 4; ++i) {
      const int f = fbase + i;
      if (!isV)
        gld16(&krow[(size_t)(f * 8 + l8) * DMODEL + swz], &Kst[0][f * 512]);
      else
        gld16(&vg[(size_t)(f * 8 + l8) * SEQ + swz], &Vst[0][f * 512]);
    }
  }
  __syncthreads();  // prologue DMA drained

  for (int kt = 0; kt < SEQ / 64; ++kt) {
    const int cur = kt & 1;
    // issue NEXT iter's DMA first (lands during this iter's compute)
    if (kt + 1 < SEQ / 64) {
#pragma unroll
      for (int i = 0; i < 4; ++i) {
        const int f = fbase + i;
        if (!isV)
          gld16(&krow[(size_t)((kt + 1) * 64 + f * 8 + l8) * DMODEL + swz],
                &Kst[cur ^ 1][f * 512]);
        else
          gld16(&vg[(size_t)(f * 8 + l8) * SEQ + (kt + 1) * 64 + swz],
                &Vst[cur ^ 1][f * 512]);
      }
    }

    const ushort* Kc = &Kst[cur][0];
    const ushort* Vc = &Vst[cur][0];

    // S^T = K-tile @ Q^T : accs[kb] covers keys kb*32..+31 x 32 q-rows
    f32x16 accs[2];
#pragma unroll
    for (int kb = 0; kb < 2; ++kb)
#pragma unroll
      for (int e = 0; e < 16; ++e) accs[kb][e] = 0.f;
#pragma unroll
    for (int kb = 0; kb < 2; ++kb)
#pragma unroll
      for (int ks = 0; ks < 4; ++ks) {
        const short8 kf = *(const short8*)
            &Kc[(kb * 32 + l31) * 64 + (((ks * 2 + hi) ^ l7) * 8)];
        accs[kb] = __builtin_amdgcn_mfma_f32_32x32x16_bf16(kf, qf[ks],
                                                           accs[kb], 0, 0, 0);
      }

    // hoist V fragment reads; ds latency hides under softmax VALU below
    short8 vf[4][2];
#pragma unroll
    for (int sg = 0; sg < 4; ++sg)
#pragma unroll
      for (int db = 0; db < 2; ++db)
        vf[sg][db] = *(const short8*)
            &Vc[(db * 32 + l31) * 64 + (((sg * 2 + hi) ^ l7) * 8)];

    // p = 2^s (Q pre-scaled); lane-partial l (lane owns q-column l31)
#pragma unroll
    for (int kb = 0; kb < 2; ++kb)
#pragma unroll
      for (int e = 0; e < 16; ++e) {
        const float p = __builtin_amdgcn_exp2f(accs[kb][e]);
        accs[kb][e] = p;
        l_i += p;
      }

    // in-register pack + lane-half exchange -> PV A-fragments pa[4]
    // lane holds k = 8o + 4hi + 2u (+1) in word w[o][u]; A-frag slice sl
    // needs k = 16sl + 8hi + j:  (word0,word2)=swap(w[2sl][0], w[2sl+1][0]),
    //                            (word1,word3)=swap(w[2sl][1], w[2sl+1][1])
    short8 pa[4];
#pragma unroll
    for (int kb = 0; kb < 2; ++kb) {
      unsigned wq[4][2];
#pragma unroll
      for (int o = 0; o < 4; ++o) {
        asm("v_cvt_pk_bf16_f32 %0, %1, %2"
            : "=v"(wq[o][0])
            : "v"(accs[kb][4 * o + 0]), "v"(accs[kb][4 * o + 1]));
        asm("v_cvt_pk_bf16_f32 %0, %1, %2"
            : "=v"(wq[o][1])
            : "v"(accs[kb][4 * o + 2]), "v"(accs[kb][4 * o + 3]));
      }
#pragma unroll
      for (int sl = 0; sl < 2; ++sl) {
        uint2v r02 = __builtin_amdgcn_permlane32_swap(wq[2 * sl][0],
                                                      wq[2 * sl + 1][0],
                                                      false, false);
        uint2v r13 = __builtin_amdgcn_permlane32_swap(wq[2 * sl][1],
                                                      wq[2 * sl + 1][1],
                                                      false, false);
        uint4v pk = {r02.x, r13.x, r02.y, r13.y};
        pa[kb * 2 + sl] = __builtin_bit_cast(short8, pk);
      }
    }

    // O += P @ V
#pragma unroll
    for (int sg = 0; sg < 4; ++sg)
#pragma unroll
      for (int db = 0; db < 2; ++db)
        acc_o[db] = __builtin_amdgcn_mfma_f32_32x32x16_bf16(pa[sg], vf[sg][db],
                                                            acc_o[db], 0, 0, 0);

    __syncthreads();  // reads of [cur] done + next DMA drained
  }

  // epilogue: complete l over both lane halves, broadcast per output row,
  // normalize, write bf16 row-major [4096][1024]
  l_i += __shfl_xor(l_i, 32);
  const float inv = 1.0f / l_i;  // for q-column l31 (both halves hold it)
#pragma unroll
  for (int o = 0; o < 4; ++o)
#pragma unroll
    for (int r0 = 0; r0 < 4; ++r0) {
      const int row = o * 8 + r0 + 4 * hi;             // q-row of reg e=4o+r0
      const float invr = __shfl(inv, row, 64);         // lane 'row' holds it
      const int s = qt * 128 + w * 32 + row;
#pragma unroll
      for (int db = 0; db < 2; ++db)
        Og[(size_t)(b * SEQ + s) * DMODEL + h * DH + db * 32 + l31] =
            f2bf(acc_o[db][4 * o + r0] * invr);
    }
}

// ---------------------------------------------------------------------------
// Output projection: out = aws[4096,1024] @ WoT^T + bo (fp32). 64x128 tile,
// BK=64, global_load_lds staging, 512 blocks.
// ---------------------------------------------------------------------------
__global__ __launch_bounds__(256) void mfma_gemm_out(const ushort* __restrict__ A,
                                                     const ushort* __restrict__ Bt,
                                                     const float* __restrict__ bias,
                                                     float* __restrict__ dst) {
  __shared__ __align__(16) ushort As[64 * 64];
  __shared__ __align__(16) ushort Bs[128 * 64];
  const int t = threadIdx.x;
  const int w = t >> 6, lane = t & 63, ln = lane & 15, q = lane >> 4;
  const int wm = w & 1, wn = w >> 1;
  const int row0 = blockIdx.y * 64, col0 = blockIdx.x * 128;
  const int sw = ln & 7;

  f32x4 acc[2][4];
#pragma unroll
  for (int i = 0; i < 2; ++i)
#pragma unroll
    for (int j = 0; j < 4; ++j) acc[i][j] = (f32x4){0.f, 0.f, 0.f, 0.f};

  for (int k0 = 0; k0 < DMODEL; k0 += 64) {
    __syncthreads();
#pragma unroll
    for (int rep = 0; rep < 2; ++rep) {
      const int u0 = rep * 256 + w * 64;
      const int u = u0 + lane;
      const int r = u >> 3, gl = (u & 7) ^ (r & 7);
      gld16(&A[(size_t)(row0 + r) * DMODEL + k0 + gl * 8], &As[u0 * 8]);
    }
#pragma unroll
    for (int rep = 0; rep < 4; ++rep) {
      const int u0 = rep * 256 + w * 64;
      const int u = u0 + lane;
      const int r = u >> 3, gl = (u & 7) ^ (r & 7);
      gld16(&Bt[(size_t)(col0 + r) * DMODEL + k0 + gl * 8], &Bs[u0 * 8]);
    }
    __syncthreads();
#pragma unroll
    for (int ks = 0; ks < 2; ++ks) {
      short8 af[2], bf[4];
#pragma unroll
      for (int rt = 0; rt < 2; ++rt)
        af[rt] = *(const short8*)&As[(wm * 32 + rt * 16 + ln) * 64 +
                                     (((ks * 4 + q) ^ sw) * 8)];
#pragma unroll
      for (int ct = 0; ct < 4; ++ct)
        bf[ct] = *(const short8*)&Bs[(wn * 64 + ct * 16 + ln) * 64 +
                                     (((ks * 4 + q) ^ sw) * 8)];
#pragma unroll
      for (int rt = 0; rt < 2; ++rt)
#pragma unroll
        for (int ct = 0; ct < 4; ++ct)
          acc[rt][ct] = __builtin_amdgcn_mfma_f32_16x16x32_bf16(af[rt], bf[ct],
                                                                acc[rt][ct], 0, 0, 0);
    }
  }

#pragma unroll
  for (int rt = 0; rt < 2; ++rt)
#pragma unroll
    for (int ct = 0; ct < 4; ++ct) {
      const int c = col0 + wn * 64 + ct * 16 + ln;
      const float bi = bias[c];
#pragma unroll
      for (int reg = 0; reg < 4; ++reg) {
        const int r = row0 + wm * 32 + rt * 16 + q * 4 + reg;
        dst[(size_t)r * DMODEL + c] = acc[rt][ct][reg] + bi;
      }
    }
}

extern "C" void kernel_launch(void* const* d_in, const int* in_sizes, int n_in,
                              void* d_out, int out_size, void* d_ws,
                              size_t ws_size, hipStream_t stream) {
  const float* patch = (const float*)d_in[0];
  const float* pixel = (const float*)d_in[1];
  const float* Wq = (const float*)d_in[2];
  const float* Wk = (const float*)d_in[3];
  const float* Wv = (const float*)d_in[4];
  const float* Wo = (const float*)d_in[5];
  const float* bo = (const float*)d_in[6];
  float* out = (float*)d_out;

  const size_t E = (size_t)2 * SEQ * DMODEL;  // 4,194,304
  const size_t W = (size_t)DMODEL * DMODEL;   // 1,048,576
  ushort* pb  = (ushort*)d_ws;      // patch bf16
  ushort* xb  = pb + E;             // pixel bf16
  ushort* wqt = xb + E;             // Wq^T * QSCALE bf16 [N][K]
  ushort* wkt = wqt + W;
  ushort* wvt = wkt + W;
  ushort* wot = wvt + W;            // live until mfma_gemm_out
  ushort* qws = wot + W;            // Q row-major [4096][1024] bf16
  ushort* kws = qws + E;            // K row-major [4096][1024] bf16
  ushort* vws = kws + E;            // V^T [bh][64][SEQ] bf16
  ushort* aws = vws + E;            // [4096][1024] row-major bf16

  prologue<<<dim3(32, 32, 6), dim3(32, 8), 0, stream>>>(
      patch, pixel, Wq, Wk, Wv, Wo, pb, xb, wqt, wkt, wvt, wot);
  mfma_gemm_qkv<<<dim3(8, 32, 3), 256, 0, stream>>>(pb, xb, wqt, wkt, wvt,
                                                    qws, kws, vws);
  flash_mfma<<<dim3(32, 16), 256, 0, stream>>>(qws, kws, vws, aws);
  mfma_gemm_out<<<dim3(8, 64), 256, 0, stream>>>(aws, wot, bo, out);
}